// Round 4
// baseline (50.408 us; speedup 1.0000x reference)
//
#include <hip/hip_runtime.h>

// Circular conv1d: x (B=64, C_in=8, L=65536) fp32, W (8,8,4), b (8,),
// circular pad by FS-1=3, stride 1. Memory-bound (floor ~31.5us at 6.3TB/s
// with L3 absorbing ~half the reads). R2 was latency-limited: only 4
// outstanding loads/wave, ~2.5 waves/SIMD. This version stages the x-tile
// through LDS so each wave issues 8 independent float4 loads back-to-back,
// and compute runs branch-free from LDS.
#define BATCH 64
#define CIN 8
#define COUT 8
#define LEN 65536
#define FS 4
#define TILE 1024          // output positions per block (256 threads x 4)
#define PADL (TILE + 8)    // +3 halo, rounded up (keeps 16B alignment)

// native clang vector type: __builtin_nontemporal_store requires a real
// vector (HIP's float4 is a struct and is rejected)
typedef float floatx4 __attribute__((ext_vector_type(4)));

__global__ __launch_bounds__(256, 4) void conv_pbc_kernel(
    const float* __restrict__ x,
    const float* __restrict__ W,
    const float* __restrict__ bias,
    float* __restrict__ out)
{
    __shared__ float sX[CIN][PADL];          // 8 x 1032 floats = 33 KB
    __shared__ float sW[COUT * CIN * FS];    // 256 floats
    __shared__ float sB[COUT];

    const int tid = threadIdx.x;
    if (tid < COUT * CIN * FS) sW[tid] = W[tid];
    if (tid < COUT)            sB[tid] = bias[tid];

    const int blocksPerBatch = LEN / TILE;              // 64
    const int b    = blockIdx.x / blocksPerBatch;
    const int tile = blockIdx.x % blocksPerBatch;
    const int base = tile * TILE;

    const float* xb = x + (size_t)b * CIN * LEN;

    // ---- Stage: 1 float4 per thread per channel, loads batched in regs ----
    floatx4 r[CIN];
#pragma unroll
    for (int ci = 0; ci < CIN; ++ci)
        r[ci] = *reinterpret_cast<const floatx4*>(xb + (size_t)ci * LEN + base + tid * 4);
#pragma unroll
    for (int ci = 0; ci < CIN; ++ci)
        *reinterpret_cast<floatx4*>(&sX[ci][tid * 4]) = r[ci];

    // Halo: 3 wrap-around floats per channel (load 4, aligned; wrap matters
    // only on the last tile of each batch row).
    if (tid < CIN) {
        const int hbase = (base + TILE) & (LEN - 1);
        const floatx4 h = *reinterpret_cast<const floatx4*>(xb + (size_t)tid * LEN + hbase);
        sX[tid][TILE + 0] = h.x;
        sX[tid][TILE + 1] = h.y;
        sX[tid][TILE + 2] = h.z;
        sX[tid][TILE + 3] = h.w;
    }
    __syncthreads();

    // ---- Compute: 4 outputs x 8 c_out per thread, all from LDS ----
    float acc[COUT][4];
#pragma unroll
    for (int co = 0; co < COUT; ++co) {
        const float bb = sB[co];
        acc[co][0] = bb; acc[co][1] = bb; acc[co][2] = bb; acc[co][3] = bb;
    }

#pragma unroll
    for (int ci = 0; ci < CIN; ++ci) {
        // two contiguous, 16B-aligned ds_read_b128 per channel; conflict-free
        const floatx4 a = *reinterpret_cast<const floatx4*>(&sX[ci][tid * 4]);
        const floatx4 q = *reinterpret_cast<const floatx4*>(&sX[ci][tid * 4 + 4]);
        const float xv[8] = {a.x, a.y, a.z, a.w, q.x, q.y, q.z, q.w};

#pragma unroll
        for (int co = 0; co < COUT; ++co) {
#pragma unroll
            for (int k = 0; k < FS; ++k) {
                const float w = sW[(co * CIN + ci) * FS + k];  // wave-uniform
#pragma unroll
                for (int p = 0; p < 4; ++p)
                    acc[co][p] += w * xv[p + k];
            }
        }
    }

    // ---- Store: nontemporal — output is never re-read; keep L3 for x ----
    float* ob = out + (size_t)b * COUT * LEN + base + tid * 4;
#pragma unroll
    for (int co = 0; co < COUT; ++co) {
        floatx4 v;
        v.x = acc[co][0]; v.y = acc[co][1]; v.z = acc[co][2]; v.w = acc[co][3];
        __builtin_nontemporal_store(v, reinterpret_cast<floatx4*>(ob + (size_t)co * LEN));
    }
}

extern "C" void kernel_launch(void* const* d_in, const int* in_sizes, int n_in,
                              void* d_out, int out_size, void* d_ws, size_t ws_size,
                              hipStream_t stream) {
    const float* x    = (const float*)d_in[0];
    const float* W    = (const float*)d_in[1];
    const float* bias = (const float*)d_in[2];
    float* out = (float*)d_out;

    const int blocksPerBatch = LEN / TILE;            // 64
    const dim3 grid(BATCH * blocksPerBatch);          // 4096 blocks
    const dim3 block(256);
    conv_pbc_kernel<<<grid, block, 0, stream>>>(x, W, bias, out);
}